// Round 6
// baseline (8095.190 us; speedup 1.0000x reference)
//
#include <hip/hip_runtime.h>

#define T_STEPS 512
#define BATCH   64
#define DIM     1024
#define HID     1024
#define G4      4096   // 4*HID
#define TCH     64     // timesteps per Xproj chunk (ring buffer)

typedef __attribute__((ext_vector_type(8))) short s8v;    // 8 bf16 = 4 VGPR
typedef __attribute__((ext_vector_type(4))) float f32x4;

__device__ __forceinline__ unsigned short f2bf(float f) {
    unsigned int u = __float_as_uint(f);
    u = u + 0x7FFFu + ((u >> 16) & 1u);       // RNE; values bounded, no inf/nan
    return (unsigned short)(u >> 16);
}
__device__ __forceinline__ float bf2f(unsigned short s) {
    return __uint_as_float(((unsigned int)s) << 16);
}

// ---------------------------------------------------------------------------
// Fragment convention (A and B share it -> result exact for any HW k-order):
//   A: row = l&15, k = ks*32 + (l>>4)*8 + e     (row = batch within m-tile)
//   B: col = l&15, k = ks*32 + (l>>4)*8 + e     (col = gate-col c)
//   D (m89-verified): col = l&15, row = (l>>4)*4 + reg
// Packed planes:
//   wP[bid][ks<64][l][e] : ks<32 -> W_ih cols, ks>=32 -> W_hh cols
//   hP[par][ks<32][m][l][e]
// Xproj ring (fp32, biases folded): Xp[t%64][bid][b][c]
// ---------------------------------------------------------------------------

__global__ __launch_bounds__(256) void pack_w(
    const float* __restrict__ Wih, const float* __restrict__ Whh,
    unsigned short* __restrict__ hi, unsigned short* __restrict__ lo)
{
    const size_t tau = (size_t)blockIdx.x * 256 + threadIdx.x;  // < 1,048,576
    const int l   = (int)(tau & 63);
    const int ks  = (int)((tau >> 6) & 63);
    const int bid = (int)(tau >> 12);
    const int c   = l & 15;
    const int n   = (c >> 2) * HID + bid * 4 + (c & 3);
    const int k   = ks * 32 + (l >> 4) * 8;
    const float* src = (k < DIM) ? (Wih + (size_t)n * DIM + k)
                                 : (Whh + (size_t)n * HID + (k - DIM));
    float f[8];
    *(float4*)&f[0] = *(const float4*)src;
    *(float4*)&f[4] = *(const float4*)(src + 4);
    s8v vh, vl;
#pragma unroll
    for (int e = 0; e < 8; ++e) {
        const unsigned short h8 = f2bf(f[e]);
        vh[e] = (short)h8;
        vl[e] = (short)f2bf(f[e] - bf2f(h8));
    }
    *(s8v*)(hi + tau * 8) = vh;
    *(s8v*)(lo + tau * 8) = vl;
}

__global__ __launch_bounds__(256) void pack_h0(
    const float* __restrict__ h0, unsigned short* __restrict__ hi,
    unsigned short* __restrict__ lo)
{
    const size_t tau = (size_t)blockIdx.x * 256 + threadIdx.x;  // < 8192 (par=0)
    const int l  = (int)(tau & 63);
    const int m  = (int)((tau >> 6) & 3);
    const int ks = (int)(tau >> 8);
    const int b  = 16 * m + (l & 15);
    const int j  = ks * 32 + (l >> 4) * 8;
    const float* src = h0 + (size_t)b * HID + j;
    float f[8];
    *(float4*)&f[0] = *(const float4*)src;
    *(float4*)&f[4] = *(const float4*)(src + 4);
    s8v vh, vl;
#pragma unroll
    for (int e = 0; e < 8; ++e) {
        const unsigned short h8 = f2bf(f[e]);
        vh[e] = (short)h8;
        vl[e] = (short)f2bf(f[e] - bf2f(h8));
    }
    *(s8v*)(hi + tau * 8) = vh;
    *(s8v*)(lo + tau * 8) = vl;
}

// ---------------------------------------------------------------------------
// Xproj chunk GEMM: grid = TCH*64 blocks (tloc = blk>>6, ng = blk&63),
// 512 threads (8 waves). wave wv: mg = wv>>2 -> m-tiles 2mg,2mg+1;
// nq = wv&3 -> bid = ng*4+nq  (ng 0..63 -> bid 0..255: FULL coverage —
// v5 bug was ng 0..15, leaving 3/4 of Xp uninitialized).
// x is split to bf16 hi/lo on the fly from raw fp32 (no xP planes needed).
// 3-pass split precision; biases folded into the output.
// ---------------------------------------------------------------------------
__global__ __launch_bounds__(512) void xproj_chunk(
    int t0,
    const float* __restrict__ inp,           // [T][B][DIM]
    const unsigned short* __restrict__ wPHi,
    const unsigned short* __restrict__ wPLo,
    const float* __restrict__ bih, const float* __restrict__ bhh,
    float* __restrict__ Xp)                  // ring [TCH][256][64][16]
{
    const int tid  = threadIdx.x;
    const int wv   = __builtin_amdgcn_readfirstlane(tid >> 6);
    const int l    = tid & 63;
    const int tloc = blockIdx.x >> 6;        // 0..TCH-1
    const int ng   = blockIdx.x & 63;        // 0..63
    const int t    = t0 + tloc;
    const int mg   = wv >> 2, nq = wv & 3;
    const int bid  = ng * 4 + nq;            // 0..255
    const int m0   = 2 * mg, m1 = m0 + 1;

    const int rowa = l & 15;          // batch row within m-tile
    const int koff = (l >> 4) * 8;    // k offset within a ks step

    const float* xbase = inp + (size_t)t * BATCH * DIM;
    const unsigned short* bHiP = wPHi + ((size_t)bid * 64) * 512;  // ks<32: W_ih
    const unsigned short* bLoP = wPLo + ((size_t)bid * 64) * 512;

    f32x4 acc0 = {0.f, 0.f, 0.f, 0.f};
    f32x4 acc1 = {0.f, 0.f, 0.f, 0.f};

    float4 x0a, x0b, x1a, x1b;
    s8v Bh, Bl;
    {
        const float* p0 = xbase + (16 * m0 + rowa) * DIM + koff;
        const float* p1 = xbase + (16 * m1 + rowa) * DIM + koff;
        x0a = *(const float4*)p0; x0b = *(const float4*)(p0 + 4);
        x1a = *(const float4*)p1; x1b = *(const float4*)(p1 + 4);
        Bh = *(const s8v*)(bHiP + l * 8);
        Bl = *(const s8v*)(bLoP + l * 8);
    }

#pragma unroll 4
    for (int i = 0; i < 32; ++i) {
        // convert current raw x -> hi/lo fragments
        float f0[8], f1[8];
        *(float4*)&f0[0] = x0a; *(float4*)&f0[4] = x0b;
        *(float4*)&f1[0] = x1a; *(float4*)&f1[4] = x1b;
        s8v A0h, A0l, A1h, A1l;
#pragma unroll
        for (int e = 0; e < 8; ++e) {
            const unsigned short h0e = f2bf(f0[e]);
            A0h[e] = (short)h0e;
            A0l[e] = (short)f2bf(f0[e] - bf2f(h0e));
            const unsigned short h1e = f2bf(f1[e]);
            A1h[e] = (short)h1e;
            A1l[e] = (short)f2bf(f1[e] - bf2f(h1e));
        }
        // prefetch next ks
        float4 n0a, n0b, n1a, n1b; s8v nBh, nBl;
        if (i < 31) {
            const int k = (i + 1) * 32 + koff;
            const float* p0 = xbase + (16 * m0 + rowa) * DIM + k;
            const float* p1 = xbase + (16 * m1 + rowa) * DIM + k;
            n0a = *(const float4*)p0; n0b = *(const float4*)(p0 + 4);
            n1a = *(const float4*)p1; n1b = *(const float4*)(p1 + 4);
            nBh = *(const s8v*)(bHiP + (size_t)(i + 1) * 512 + l * 8);
            nBl = *(const s8v*)(bLoP + (size_t)(i + 1) * 512 + l * 8);
        }
        acc0 = __builtin_amdgcn_mfma_f32_16x16x32_bf16(A0h, Bh, acc0, 0, 0, 0);
        acc1 = __builtin_amdgcn_mfma_f32_16x16x32_bf16(A1h, Bh, acc1, 0, 0, 0);
        acc0 = __builtin_amdgcn_mfma_f32_16x16x32_bf16(A0h, Bl, acc0, 0, 0, 0);
        acc1 = __builtin_amdgcn_mfma_f32_16x16x32_bf16(A1h, Bl, acc1, 0, 0, 0);
        acc0 = __builtin_amdgcn_mfma_f32_16x16x32_bf16(A0l, Bh, acc0, 0, 0, 0);
        acc1 = __builtin_amdgcn_mfma_f32_16x16x32_bf16(A1l, Bh, acc1, 0, 0, 0);
        x0a = n0a; x0b = n0b; x1a = n1a; x1b = n1b; Bh = nBh; Bl = nBl;
    }

    // epilogue: fold biases, write Xp ring
    const int col = l & 15;
    const int n   = (col >> 2) * HID + bid * 4 + (col & 3);
    const float bias = bih[n] + bhh[n];
    const int tc = t & (TCH - 1);
    float* op = Xp + (((size_t)tc * 256 + bid) * 64) * 16;
#pragma unroll
    for (int r = 0; r < 4; ++r) {
        const int row = (l >> 4) * 4 + r;
        op[(16 * m0 + row) * 16 + col] = acc0[r] + bias;
        op[(16 * m1 + row) * 16 + col] = acc1[r] + bias;
    }
}

// ---------------------------------------------------------------------------
// Per-step MFMA kernel (h.W_hh only, K=1024): 256 blocks x 512 threads.
// wave wv: mg = wv>>2 -> m-tiles 2mg,2mg+1; kq = wv&3 -> ks in [kq*8, kq*8+8).
// Per-XCD W_hh working set = 32 blocks x 65 KB = 2.1 MB -> L2-resident.
// No LDS in main loop; 2 barriers for the 4-way k-reduce; tail adds Xp.
// ---------------------------------------------------------------------------
__global__ __launch_bounds__(512) void lstm_step_mfma(
    int t,
    const unsigned short* __restrict__ wPHi, const unsigned short* __restrict__ wPLo,
    const unsigned short* __restrict__ hPHi, const unsigned short* __restrict__ hPLo,
    unsigned short* __restrict__ hPHiW,      unsigned short* __restrict__ hPLoW,
    const float* __restrict__ Xp,            // ring [TCH][256][64][16]
    const float* __restrict__ cprev,
    float* __restrict__ cbuf, float* __restrict__ out, float* __restrict__ tailp)
{
    __shared__ float part_s[8][64][8];    // 16 KB
    __shared__ float gates_s[64][17];     // 4.4 KB

    const int bid = blockIdx.x;
    const int tid = threadIdx.x;
    const int wv  = __builtin_amdgcn_readfirstlane(tid >> 6);
    const int l   = tid & 63;
    const int mg  = wv >> 2;             // 0..1
    const int kq  = wv & 3;              // k-quarter (8 ks each)
    const int par = t & 1;
    const int m0  = 2 * mg, m1 = 2 * mg + 1;

    const unsigned short* aHi = hPHi + ((size_t)par * 32 + kq * 8) * 2048;
    const unsigned short* aLo = hPLo + ((size_t)par * 32 + kq * 8) * 2048;
    const unsigned short* bHiP = wPHi + ((size_t)bid * 64 + 32 + kq * 8) * 512;
    const unsigned short* bLoP = wPLo + ((size_t)bid * 64 + 32 + kq * 8) * 512;

#define LDA(P, i, m) (*(const s8v*)((P) + ((size_t)(i) * 2048 + (m) * 512 + l * 8)))
#define LDB(P, i)    (*(const s8v*)((P) + ((size_t)(i) * 512 + l * 8)))

    f32x4 acc0 = {0.f, 0.f, 0.f, 0.f};
    f32x4 acc1 = {0.f, 0.f, 0.f, 0.f};

    s8v A0h = LDA(aHi, 0, m0), A0l = LDA(aLo, 0, m0);
    s8v A1h = LDA(aHi, 0, m1), A1l = LDA(aLo, 0, m1);
    s8v Bh  = LDB(bHiP, 0),    Bl  = LDB(bLoP, 0);

#pragma unroll 4
    for (int i = 0; i < 8; ++i) {
        s8v nA0h, nA0l, nA1h, nA1l, nBh, nBl;
        if (i < 7) {
            nA0h = LDA(aHi, i + 1, m0); nA0l = LDA(aLo, i + 1, m0);
            nA1h = LDA(aHi, i + 1, m1); nA1l = LDA(aLo, i + 1, m1);
            nBh  = LDB(bHiP, i + 1);    nBl  = LDB(bLoP, i + 1);
        }
        acc0 = __builtin_amdgcn_mfma_f32_16x16x32_bf16(A0h, Bh, acc0, 0, 0, 0);
        acc1 = __builtin_amdgcn_mfma_f32_16x16x32_bf16(A1h, Bh, acc1, 0, 0, 0);
        acc0 = __builtin_amdgcn_mfma_f32_16x16x32_bf16(A0h, Bl, acc0, 0, 0, 0);
        acc1 = __builtin_amdgcn_mfma_f32_16x16x32_bf16(A1h, Bl, acc1, 0, 0, 0);
        acc0 = __builtin_amdgcn_mfma_f32_16x16x32_bf16(A0l, Bh, acc0, 0, 0, 0);
        acc1 = __builtin_amdgcn_mfma_f32_16x16x32_bf16(A1l, Bh, acc1, 0, 0, 0);
        A0h = nA0h; A0l = nA0l; A1h = nA1h; A1l = nA1l; Bh = nBh; Bl = nBl;
    }
#undef LDA
#undef LDB

    // --- 4-way k-reduce through LDS (2 barriers) ---
    *(f32x4*)&part_s[wv][l][0] = acc0;
    *(f32x4*)&part_s[wv][l][4] = acc1;
    __syncthreads();
    if (tid < 128) {
        const int mg2 = tid >> 6, l2 = tid & 63;
        f32x4 s0 = {0.f, 0.f, 0.f, 0.f};
        f32x4 s1 = {0.f, 0.f, 0.f, 0.f};
#pragma unroll
        for (int k = 0; k < 4; ++k) {
            s0 += *(const f32x4*)&part_s[mg2 * 4 + k][l2][0];
            s1 += *(const f32x4*)&part_s[mg2 * 4 + k][l2][4];
        }
        const int c = l2 & 15, rb = (l2 >> 4) * 4;
#pragma unroll
        for (int r = 0; r < 4; ++r) {
            gates_s[16 * (2 * mg2 + 0) + rb + r][c] = s0[r];
            gates_s[16 * (2 * mg2 + 1) + rb + r][c] = s1[r];
        }
    }
    __syncthreads();

    // --- elementwise LSTM cell update + h repack for next step ---
    if (tid < 256) {
        const int b  = tid >> 2;
        const int jj = tid & 3;
        const int j  = bid * 4 + jj;
        const int tc = t & (TCH - 1);
        const float* xp = Xp + (((size_t)tc * 256 + bid) * 64 + b) * 16;
        const float pre_i = gates_s[b][0  + jj] + xp[0  + jj];
        const float pre_f = gates_s[b][4  + jj] + xp[4  + jj];
        const float pre_g = gates_s[b][8  + jj] + xp[8  + jj];
        const float pre_o = gates_s[b][12 + jj] + xp[12 + jj];
        const float ig = 1.0f / (1.0f + __expf(-pre_i));
        const float fg = 1.0f / (1.0f + __expf(-pre_f));
        const float gg = tanhf(pre_g);
        const float og = 1.0f / (1.0f + __expf(-pre_o));
        const float cp = cprev[b * HID + j];
        const float cn = fg * cp + ig * gg;
        const float hn = og * tanhf(cn);
        cbuf[b * HID + j] = cn;
        out[((size_t)t * BATCH + b) * HID + j] = hn;
        if (t == T_STEPS - 1) {
            tailp[b * HID + j] = hn;                              // h_T
            tailp[(size_t)BATCH * HID + b * HID + j] = cn;        // c_T
        }
        // repack hn into fragment planes, parity par^1
        const int parn = par ^ 1;
        const unsigned short hhi = f2bf(hn);
        const unsigned short hlo = f2bf(hn - bf2f(hhi));
        const size_t idx = ((((size_t)parn * 32 + (j >> 5)) * 4 + (b >> 4)) * 64
                            + ((b & 15) + 16 * ((j & 31) >> 3))) * 8 + (j & 7);
        hPHiW[idx] = hhi;
        hPLoW[idx] = hlo;
    }
}

// ---------------------------------------------------------------------------
// Fallback (proven v2): fused fp32 per-step kernel, wave-private LDS staging.
// ---------------------------------------------------------------------------
__global__ __launch_bounds__(512) void lstm_step_f32(
    const float* __restrict__ x, const float* __restrict__ hprev,
    const float* __restrict__ cprev,
    const float* __restrict__ Wih, const float* __restrict__ Whh,
    const float* __restrict__ bih, const float* __restrict__ bhh,
    float* __restrict__ cnext, float* __restrict__ hout,
    float* __restrict__ tail)
{
    __shared__ float h_s[8][16][68];
    __shared__ float w_s[8][16][20];
    __shared__ float gates_s[64][17];
    float* part_s = &h_s[0][0][0];

    const int bid = blockIdx.x;
    const int tid = threadIdx.x;
    const int j0  = bid * 4;
    const int wv  = tid >> 6;
    const int gl  = tid & 63;
    const int b0  = (gl >> 2) * 4;
    const int c0_ = (gl & 3) * 4;

    const float* __restrict__ src = (wv < 4) ? x   : hprev;
    const float* __restrict__ W   = (wv < 4) ? Wih : Whh;
    const int kbase = (wv & 3) * 256;

    float acc[4][4] = {};
    float4 hv[4], wvf;

#pragma unroll
    for (int r = 0; r < 4; ++r) {
        const int fidx = r * 64 + gl;
        hv[r] = *(const float4*)(src + (fidx >> 2) * DIM + kbase + (fidx & 3) * 4);
    }
    {
        const int c = gl >> 2, k4 = (gl & 3) * 4;
        const int n = (c >> 2) * HID + j0 + (c & 3);
        wvf = *(const float4*)(W + (size_t)n * DIM + kbase + k4);
    }

    for (int ci = 0; ci < 16; ++ci) {
#pragma unroll
        for (int r = 0; r < 4; ++r) {
            const int fidx = r * 64 + gl;
            const int b = fidx >> 2, k4 = (fidx & 3) * 4;
            h_s[wv][k4 + 0][b] = hv[r].x; h_s[wv][k4 + 1][b] = hv[r].y;
            h_s[wv][k4 + 2][b] = hv[r].z; h_s[wv][k4 + 3][b] = hv[r].w;
        }
        {
            const int c = gl >> 2, k4 = (gl & 3) * 4;
            w_s[wv][k4 + 0][c] = wvf.x; w_s[wv][k4 + 1][c] = wvf.y;
            w_s[wv][k4 + 2][c] = wvf.z; w_s[wv][k4 + 3][c] = wvf.w;
        }
        if (ci < 15) {
            const int kb = kbase + (ci + 1) * 16;
#pragma unroll
            for (int r = 0; r < 4; ++r) {
                const int fidx = r * 64 + gl;
                hv[r] = *(const float4*)(src + (fidx >> 2) * DIM + kb + (fidx & 3) * 4);
            }
            {
                const int c = gl >> 2, k4 = (gl & 3) * 4;
                const int n = (c >> 2) * HID + j0 + (c & 3);
                wvf = *(const float4*)(W + (size_t)n * DIM + kb + k4);
            }
        }
#pragma unroll
        for (int kk = 0; kk < 16; ++kk) {
            const float4 h4 = *(const float4*)&h_s[wv][kk][b0];
            const float4 w4 = *(const float4*)&w_s[wv][kk][c0_];
            const float hr[4] = {h4.x, h4.y, h4.z, h4.w};
            const float wr[4] = {w4.x, w4.y, w4.z, w4.w};
#pragma unroll
            for (int i = 0; i < 4; ++i)
#pragma unroll
                for (int j = 0; j < 4; ++j)
                    acc[i][j] += hr[i] * wr[j];
        }
    }

    __syncthreads();
#pragma unroll
    for (int i = 0; i < 4; ++i)
#pragma unroll
        for (int j = 0; j < 4; ++j)
            part_s[tid * 17 + i * 4 + j] = acc[i][j];
    __syncthreads();
    if (tid < 64) {
#pragma unroll
        for (int i = 0; i < 4; ++i)
#pragma unroll
            for (int j = 0; j < 4; ++j) {
                const int idx = i * 4 + j;
                float s = 0.0f;
#pragma unroll
                for (int p = 0; p < 8; ++p)
                    s += part_s[(gl + 64 * p) * 17 + idx];
                gates_s[b0 + i][c0_ + j] = s;
            }
    }
    __syncthreads();

    if (tid < 256) {
        const int b  = tid >> 2;
        const int jj = tid & 3;
        const int j  = j0 + jj;
        const float pre_i = gates_s[b][0  + jj] + bih[0 * HID + j] + bhh[0 * HID + j];
        const float pre_f = gates_s[b][4  + jj] + bih[1 * HID + j] + bhh[1 * HID + j];
        const float pre_g = gates_s[b][8  + jj] + bih[2 * HID + j] + bhh[2 * HID + j];
        const float pre_o = gates_s[b][12 + jj] + bih[3 * HID + j] + bhh[3 * HID + j];
        const float ig = 1.0f / (1.0f + __expf(-pre_i));
        const float fg = 1.0f / (1.0f + __expf(-pre_f));
        const float gg = tanhf(pre_g);
        const float og = 1.0f / (1.0f + __expf(-pre_o));
        const float cp = cprev[b * HID + j];
        const float cn = fg * cp + ig * gg;
        const float hn = og * tanhf(cn);
        cnext[b * HID + j] = cn;
        hout[b * HID + j]  = hn;
        if (tail) {
            tail[b * HID + j] = hn;
            tail[(size_t)BATCH * HID + b * HID + j] = cn;
        }
    }
}

// ---------------------------------------------------------------------------
extern "C" void kernel_launch(void* const* d_in, const int* in_sizes, int n_in,
                              void* d_out, int out_size, void* d_ws, size_t ws_size,
                              hipStream_t stream) {
    const float* inputs = (const float*)d_in[0];
    const float* h0     = (const float*)d_in[1];
    const float* c0     = (const float*)d_in[2];
    const float* W_ih   = (const float*)d_in[3];
    const float* W_hh   = (const float*)d_in[4];
    const float* b_ih   = (const float*)d_in[5];
    const float* b_hh   = (const float*)d_in[6];
    float* out = (float*)d_out;

    const size_t WPn = (size_t)256 * 64 * 512;        // 8,388,608 shorts/plane
    const size_t HPn = (size_t)2 * 32 * 4 * 512;      //   131,072 shorts/plane
    const size_t XPn = (size_t)TCH * 256 * 64 * 16;   // 16,777,216 floats (ring)
    const size_t needB = (2 * WPn + 2 * HPn) * sizeof(unsigned short)
                       + (XPn + (size_t)BATCH * HID) * sizeof(float);  // ~101.5 MB

    if (ws_size >= needB) {
        unsigned short* wPHi = (unsigned short*)d_ws;
        unsigned short* wPLo = wPHi + WPn;
        unsigned short* hPHi = wPLo + WPn;
        unsigned short* hPLo = hPHi + HPn;
        float* Xp   = (float*)(hPLo + HPn);
        float* cbuf = Xp + XPn;
        float* tailp = out + (size_t)T_STEPS * BATCH * HID;

        pack_w<<<dim3(4096), dim3(256), 0, stream>>>(W_ih, W_hh, wPHi, wPLo);
        pack_h0<<<dim3(32),  dim3(256), 0, stream>>>(h0, hPHi, hPLo);

        for (int c = 0; c < T_STEPS / TCH; ++c) {
            xproj_chunk<<<dim3(TCH * 64), dim3(512), 0, stream>>>(
                c * TCH, inputs, wPHi, wPLo, b_ih, b_hh, Xp);
            for (int tl = 0; tl < TCH; ++tl) {
                const int t = c * TCH + tl;
                const float* cp = (t == 0) ? c0 : cbuf;
                lstm_step_mfma<<<dim3(256), dim3(512), 0, stream>>>(
                    t, wPHi, wPLo, hPHi, hPLo, hPHi, hPLo,
                    Xp, cp, cbuf, out, tailp);
            }
        }
    } else {
        float* cbuf = (float*)d_ws;
        for (int t = 0; t < T_STEPS; ++t) {
            const float* x  = inputs + (size_t)t * BATCH * DIM;
            const float* hp = (t == 0) ? h0 : out + (size_t)(t - 1) * BATCH * HID;
            const float* cp = (t == 0) ? c0 : cbuf;
            float* ho    = out + (size_t)t * BATCH * HID;
            float* tailp = (t == T_STEPS - 1)
                         ? out + (size_t)T_STEPS * BATCH * HID : nullptr;
            lstm_step_f32<<<dim3(256), dim3(512), 0, stream>>>(
                x, hp, cp, W_ih, W_hh, b_ih, b_hh, cbuf, ho, tailp);
        }
    }
}